// Round 12
// baseline (4217.363 us; speedup 1.0000x reference)
//
#include <hip/hip_runtime.h>
#include <hip/hip_bf16.h>

#define T_STEPS 512
#define INP     512
#define NB      256
#define HID     1024
#define WID     512
#define KZ      1536   // HID + INP
#define ZSZ     (NB * KZ)

typedef short          bf16x8   __attribute__((ext_vector_type(8)));
typedef float          f32x4    __attribute__((ext_vector_type(4)));
typedef float          f32x2    __attribute__((ext_vector_type(2)));
typedef unsigned short ushort8  __attribute__((ext_vector_type(8)));
typedef unsigned short ushort2v __attribute__((ext_vector_type(2)));
typedef unsigned short ushort4v __attribute__((ext_vector_type(4)));
typedef unsigned       uint4v   __attribute__((ext_vector_type(4)));
typedef unsigned long long u64;

__device__ __forceinline__ unsigned short f2bf(float x) {
  __hip_bfloat16 h = __float2bfloat16(x);
  return __builtin_bit_cast(unsigned short, h);
}
__device__ __forceinline__ float sigm(float x) { return 1.0f / (1.0f + __expf(-x)); }

// ---- z ring access, two coherence modes (round-8 proven) ----
#define ZLOAD_FAST(dst, p) \
  asm volatile("global_load_dwordx4 %0, %1, off sc0" : "=v"(dst) : "v"(p))
#define ZLOAD_SLOW(dst, p) \
  asm volatile("global_load_dwordx4 %0, %1, off sc0 sc1" : "=v"(dst) : "v"(p))
#define ZWAIT() do { \
  asm volatile("s_waitcnt vmcnt(0)" ::: "memory"); \
  __builtin_amdgcn_sched_barrier(0); \
} while (0)

template <bool FAST>
__device__ __forceinline__ void zst4(unsigned short* p, ushort2v v) {
  if constexpr (FAST) *(unsigned*)p = __builtin_bit_cast(unsigned, v);
  else __hip_atomic_store((unsigned*)p, __builtin_bit_cast(unsigned, v),
                          __ATOMIC_RELAXED, __HIP_MEMORY_SCOPE_AGENT);
}
template <bool FAST>
__device__ __forceinline__ void zst8(unsigned short* p, ushort4v v) {
  if constexpr (FAST) *(u64*)p = __builtin_bit_cast(u64, v);
  else __hip_atomic_store((u64*)p, __builtin_bit_cast(u64, v),
                          __ATOMIC_RELAXED, __HIP_MEMORY_SCOPE_AGENT);
}

// ---- sync primitives: ONLY proven patterns ----
// HARD RULES: spin-polls are sc0|sc1 (LLC); each poll asm is a SINGLE load
// instruction (the R7/R8/R11-proven shape — multi-load asm blocks are banned);
// slot writes are agent-scope atomic stores (single writer, monotonic).
#define SLD4(dst, p) \
  asm volatile("global_load_dwordx4 %0, %1, off sc0 sc1" : "=v"(dst) : "v"(p))
#define SLD1(dst, p) \
  asm volatile("global_load_dword %0, %1, off sc0 sc1" : "=v"(dst) : "v"(p))
#define SWAITM() asm volatile("s_waitcnt vmcnt(0)" ::: "memory")

// Slice line (64 u32): [0..15]=h-WG slots  [16..23]=x-WG slots  [24..31]=y-WG slots
// slot value = number of completed phases (monotonic, single writer).
__device__ __forceinline__ void arrive_slot(unsigned* slot, unsigned val) {
  asm volatile("s_waitcnt vmcnt(0)" ::: "memory");   // my z stores committed
  __syncthreads();                                   // whole WG drained
  if (threadIdx.x == 0)
    __hip_atomic_store(slot, val, __ATOMIC_RELAXED, __HIP_MEMORY_SCOPE_AGENT);
}
// h wave gate: producers 2w,2w+1 (one dwordx4 group) >= t, x slot w >= t,
// wave 0 additionally all 8 y slots >= yt (ring anti-dep, 2-phase slack).
__device__ __forceinline__ void gate_h(const unsigned* line, int w, unsigned t, unsigned yt) {
  const unsigned* ph = line + ((w >> 1) << 2);
  const unsigned* px = line + 16 + w;
  for (;;) {
    uint4v v; unsigned xv; uint4v y0, y1;
    SLD4(v, ph);
    SLD1(xv, px);
    if (w == 0) { SLD4(y0, line + 24); SLD4(y1, line + 28); }
    SWAITM();
    const unsigned s0 = (w & 1) ? v.z : v.x;
    const unsigned s1 = (w & 1) ? v.w : v.y;
    bool ok = (s0 >= t) && (s1 >= t) && (xv >= t);
    if (w == 0)
      ok = ok && (y0.x >= yt) && (y0.y >= yt) && (y0.z >= yt) && (y0.w >= yt)
              && (y1.x >= yt) && (y1.y >= yt) && (y1.z >= yt) && (y1.w >= yt);
    if (ok) return;
    __builtin_amdgcn_s_sleep(1);
  }
}
// y wave gate: producers 2w,2w+1 >= t
__device__ __forceinline__ void gate_y(const unsigned* line, int w, unsigned t) {
  const unsigned* ph = line + ((w >> 1) << 2);
  for (;;) {
    uint4v v;
    SLD4(v, ph);
    SWAITM();
    const unsigned s0 = (w & 1) ? v.z : v.x;
    const unsigned s1 = (w & 1) ? v.w : v.y;
    if (s0 >= t && s1 >= t) return;
    __builtin_amdgcn_s_sleep(1);
  }
}
// x gate: all 16 h slots >= t (ring anti-dep; off critical path)
__device__ __forceinline__ void gate_x(const unsigned* line, unsigned t) {
  for (;;) {
    uint4v a, b, c, d;
    SLD4(a, line);
    SLD4(b, line + 4);
    SLD4(c, line + 8);
    SLD4(d, line + 12);
    SWAITM();
    if (a.x>=t && a.y>=t && a.z>=t && a.w>=t &&
        b.x>=t && b.y>=t && b.z>=t && b.w>=t &&
        c.x>=t && c.y>=t && c.z>=t && c.w>=t &&
        d.x>=t && d.y>=t && d.z>=t && d.w>=t) return;
    __builtin_amdgcn_s_sleep(1);
  }
}

// ---------------- setup: z ring init (z_0 full, x_1 part), zero sync area ----------------
__global__ void elman_setup(const float* __restrict__ h0, const float* __restrict__ xs,
                            unsigned short* __restrict__ zT, unsigned* __restrict__ bars) {
  const int b = blockIdx.x;
  if (b == 0) {
    for (int j = threadIdx.x; j < 1024; j += blockDim.x) bars[j] = 0u;
  }
  for (int k = threadIdx.x; k < KZ; k += blockDim.x) {   // buf0 = z_0
    const float v = (k < HID) ? h0[k] : xs[(size_t)(k - HID) * NB + b];
    zT[(size_t)b * KZ + k] = f2bf(v);
  }
  for (int i = threadIdx.x; i < INP; i += blockDim.x)    // buf1 x-part = x_1
    zT[(size_t)ZSZ + (size_t)b * KZ + HID + i] = f2bf(xs[(size_t)(INP + i) * NB + b]);
}

// LDS partial buffer: 8 waves x 2 halves x [32 cols][stride 36 words]
#define PSTR 36
#define PWSZ (32 * PSTR)

// ---------------- phase loop ----------------
// 256 WGs x 512 threads. slice = wg & 7 (32 WGs: 16 h + 8 y + 8 x), 4-deep z ring.
// h wave w, phase t: x-part of z_t (rows 1024+64w..) pre-computed BEFORE the gate
//   (justified by phase t-1's gate x_slot[w] >= t-1 => x_t written; t<2 from setup);
//   then gate {h slots 2w,2w+1 >= t, x slot w >= t, (w==0) y slots >= t-2};
//   then h-part loads+MFMA; reduce; store z_{t+1}.h; arrive.
// Ring safety: zn stores happen after __syncthreads that follows ALL waves' gates
//   (union of wave gates covers h slots 0..15 and y slots via wave 0). x writes
//   x-part only; y reads h-part only (disjoint).
template <bool FAST>
__device__ __forceinline__ void run_phases(
    const float* __restrict__ xs,
    const float* __restrict__ Wh, const float* __restrict__ bh,
    const float* __restrict__ Wy, const float* __restrict__ by,
    unsigned short* __restrict__ zT, float* __restrict__ out,
    unsigned* line, float* P, int wg, int tid) {
  const int w = tid >> 6, lane = tid & 63;
  const int lr = lane & 15, lk = lane >> 4;

  if (wg < 128) {
    // ================= h role =================
    const int m0 = (wg >> 3) * 64;
    const int n0 = (wg & 7) * 32;
    const int kwh = w * 128;           // h-part: 4 kc
    const int kwx = HID + w * 64;      // x-part: 2 kc
    unsigned* slot = line + (wg >> 3);
    bf16x8 A[4][6];                    // W_h fragments (resident in unified RF)
#pragma unroll
    for (int mt = 0; mt < 4; ++mt)
#pragma unroll
      for (int kc = 0; kc < 6; ++kc) {
        const int kg = (kc < 4) ? (kwh + kc * 32) : (kwx + (kc - 4) * 32);
        const float* wp = Wh + (size_t)(m0 + mt * 16 + lr) * KZ + kg + lk * 8;
        const f32x4 f0 = *(const f32x4*)wp;
        const f32x4 f1 = *(const f32x4*)(wp + 4);
        ushort8 a;
#pragma unroll
        for (int e = 0; e < 4; ++e) { a[e] = f2bf(f0[e]); a[4 + e] = f2bf(f1[e]); }
        A[mt][kc] = __builtin_bit_cast(bf16x8, a);
      }
    const int lcol = tid >> 4;
    const int r2 = (tid & 15) * 2;
    f32x2 bias[2];
#pragma unroll
    for (int hf = 0; hf < 2; ++hf) bias[hf] = *(const f32x2*)&bh[m0 + hf * 32 + r2];
    float* Pw = P + w * (2 * PWSZ);

    for (int t = 0; t <= T_STEPS; ++t) {
      if (t < T_STEPS) {
        const unsigned short* zc = zT + (size_t)(t & 3) * ZSZ;
        unsigned short* zn = zT + (size_t)((t + 1) & 3) * ZSZ;
        const unsigned short* zbh = zc + (size_t)(n0 + lr) * KZ + kwh + lk * 8;
        const unsigned short* zbx = zc + (size_t)(n0 + lr) * KZ + kwx + lk * 8;
        // ---- pre-gate x-part (data certified by previous phase's gate) ----
        bf16x8 fx[2][2];
#pragma unroll
        for (int j = 0; j < 2; ++j)
#pragma unroll
          for (int nt = 0; nt < 2; ++nt) {
            if constexpr (FAST) ZLOAD_FAST(fx[j][nt], zbx + nt * (16 * KZ) + j * 32);
            else                ZLOAD_SLOW(fx[j][nt], zbx + nt * (16 * KZ) + j * 32);
          }
        ZWAIT();
        f32x4 acc[4][2];
#pragma unroll
        for (int mt = 0; mt < 4; ++mt)
#pragma unroll
          for (int nt = 0; nt < 2; ++nt) acc[mt][nt] = (f32x4){0.f, 0.f, 0.f, 0.f};
#pragma unroll
        for (int j = 0; j < 2; ++j)
#pragma unroll
          for (int nt = 0; nt < 2; ++nt)
#pragma unroll
            for (int mt = 0; mt < 4; ++mt)
              acc[mt][nt] = __builtin_amdgcn_mfma_f32_16x16x32_bf16(A[mt][4 + j], fx[j][nt], acc[mt][nt], 0, 0, 0);
        // ---- per-wave gate (lane 0 spins; wave reconverges after) ----
        if (t >= 1 && lane == 0)
          gate_h(line, w, (unsigned)t, (t >= 3) ? (unsigned)(t - 2) : 0u);
        // ---- h-part ----
        bf16x8 fh[4][2];
#pragma unroll
        for (int kc = 0; kc < 4; ++kc)
#pragma unroll
          for (int nt = 0; nt < 2; ++nt) {
            if constexpr (FAST) ZLOAD_FAST(fh[kc][nt], zbh + nt * (16 * KZ) + kc * 32);
            else                ZLOAD_SLOW(fh[kc][nt], zbh + nt * (16 * KZ) + kc * 32);
          }
        ZWAIT();
#pragma unroll
        for (int kc = 0; kc < 4; ++kc)
#pragma unroll
          for (int nt = 0; nt < 2; ++nt)
#pragma unroll
            for (int mt = 0; mt < 4; ++mt)
              acc[mt][nt] = __builtin_amdgcn_mfma_f32_16x16x32_bf16(A[mt][kc], fh[kc][nt], acc[mt][nt], 0, 0, 0);
        // ---- single-pass cross-wave K reduction ----
#pragma unroll
        for (int hf = 0; hf < 2; ++hf)
#pragma unroll
          for (int mp = 0; mp < 2; ++mp)
#pragma unroll
            for (int nt = 0; nt < 2; ++nt)
              *(f32x4*)&Pw[hf * PWSZ + (nt * 16 + lr) * PSTR + mp * 16 + lk * 4] = acc[hf * 2 + mp][nt];
        __syncthreads();
#pragma unroll
        for (int hf = 0; hf < 2; ++hf) {
          f32x2 s = {0.f, 0.f};
#pragma unroll
          for (int ww = 0; ww < 8; ++ww)
            s += *(const f32x2*)&P[ww * (2 * PWSZ) + hf * PWSZ + lcol * PSTR + r2];
          s += bias[hf];
          ushort2v o2;
          o2[0] = f2bf(sigm(s[0]));
          o2[1] = f2bf(sigm(s[1]));
          zst4<FAST>(zn + (size_t)(n0 + lcol) * KZ + m0 + hf * 32 + r2, o2);
        }
      }
      arrive_slot(slot, (unsigned)(t + 1));
    }

  } else if (wg < 192) {
    // ================= y role =================
    const int idx = wg - 128;
    const int m0 = (idx >> 3) * 64;
    const int n0 = (idx & 7) * 32;
    const int kw = w * 128;
    unsigned* slot = line + 24 + (idx >> 3);
    bf16x8 A[4][4];
#pragma unroll
    for (int mt = 0; mt < 4; ++mt)
#pragma unroll
      for (int kc = 0; kc < 4; ++kc) {
        const float* wp = Wy + (size_t)(m0 + mt * 16 + lr) * HID + kw + kc * 32 + lk * 8;
        const f32x4 f0 = *(const f32x4*)wp;
        const f32x4 f1 = *(const f32x4*)(wp + 4);
        ushort8 a;
#pragma unroll
        for (int e = 0; e < 4; ++e) { a[e] = f2bf(f0[e]); a[4 + e] = f2bf(f1[e]); }
        A[mt][kc] = __builtin_bit_cast(bf16x8, a);
      }
    const int lcol = tid & 31;
    const int r2 = (tid >> 5) * 2;
    f32x2 bias[2];
#pragma unroll
    for (int hf = 0; hf < 2; ++hf) bias[hf] = *(const f32x2*)&by[m0 + hf * 32 + r2];
    float* Pw = P + w * (2 * PWSZ);

    for (int t = 0; t <= T_STEPS; ++t) {
      if (t >= 1) {
        const unsigned short* zc = zT + (size_t)(t & 3) * ZSZ;
        if (lane == 0) gate_y(line, w, (unsigned)t);
        const unsigned short* zb = zc + (size_t)(n0 + lr) * KZ + kw + lk * 8;
        bf16x8 fb[4][2];
#pragma unroll
        for (int kc = 0; kc < 4; ++kc)
#pragma unroll
          for (int nt = 0; nt < 2; ++nt) {
            if constexpr (FAST) ZLOAD_FAST(fb[kc][nt], zb + nt * (16 * KZ) + kc * 32);
            else                ZLOAD_SLOW(fb[kc][nt], zb + nt * (16 * KZ) + kc * 32);
          }
        ZWAIT();
        f32x4 acc[4][2];
#pragma unroll
        for (int mt = 0; mt < 4; ++mt)
#pragma unroll
          for (int nt = 0; nt < 2; ++nt) acc[mt][nt] = (f32x4){0.f, 0.f, 0.f, 0.f};
#pragma unroll
        for (int kc = 0; kc < 4; ++kc)
#pragma unroll
          for (int nt = 0; nt < 2; ++nt)
#pragma unroll
            for (int mt = 0; mt < 4; ++mt)
              acc[mt][nt] = __builtin_amdgcn_mfma_f32_16x16x32_bf16(A[mt][kc], fb[kc][nt], acc[mt][nt], 0, 0, 0);
        float* op = out + (size_t)(t - 1) * (WID * NB);
#pragma unroll
        for (int hf = 0; hf < 2; ++hf)
#pragma unroll
          for (int mp = 0; mp < 2; ++mp)
#pragma unroll
            for (int nt = 0; nt < 2; ++nt)
              *(f32x4*)&Pw[hf * PWSZ + (nt * 16 + lr) * PSTR + mp * 16 + lk * 4] = acc[hf * 2 + mp][nt];
        __syncthreads();
#pragma unroll
        for (int hf = 0; hf < 2; ++hf) {
          f32x2 s = {0.f, 0.f};
#pragma unroll
          for (int ww = 0; ww < 8; ++ww)
            s += *(const f32x2*)&P[ww * (2 * PWSZ) + hf * PWSZ + lcol * PSTR + r2];
          s += bias[hf];
          const int row = m0 + hf * 32 + r2;
          op[(size_t)(row + 0) * NB + n0 + lcol] = sigm(s[0]);
          op[(size_t)(row + 1) * NB + n0 + lcol] = sigm(s[1]);
        }
      }
      arrive_slot(slot, (unsigned)(t + 1));
    }

  } else {
    // ================= x role (one phase ahead: writes x_{t+2}) =================
    const int xi = wg - 192;
    const int i0 = (xi >> 3) * 64;
    const int b0 = (xi & 7) * 32;
    const int c = tid & 31, rb = tid >> 5;
    unsigned* slot = line + 16 + (xi >> 3);
    for (int t = 0; t <= T_STEPS; ++t) {
      if (t <= T_STEPS - 3) {
        unsigned short* zx = zT + (size_t)((t + 2) & 3) * ZSZ;
        const float* xp = xs + (size_t)(t + 2) * (INP * NB) + (size_t)(i0 + rb * 4) * NB + b0 + c;
        ushort4v o;
#pragma unroll
        for (int j = 0; j < 4; ++j) o[j] = f2bf(xp[(size_t)j * NB]);
        if (t >= 2 && tid == 0) gate_x(line, (unsigned)(t - 1));
        __syncthreads();
        zst8<FAST>(zx + (size_t)(b0 + c) * KZ + HID + i0 + rb * 4, o);
      }
      arrive_slot(slot, (unsigned)(t + 1));
    }
  }
}

// ---------------- persistent sequential kernel ----------------
__global__ void __launch_bounds__(512, 2) elman_seq(
    const float* __restrict__ xs,
    const float* __restrict__ Wh, const float* __restrict__ bh,
    const float* __restrict__ Wy, const float* __restrict__ by,
    unsigned short* __restrict__ zT, float* __restrict__ out,
    unsigned* __restrict__ bars) {
  __shared__ float P[16 * PWSZ];
  __shared__ unsigned modeSh;
  const int wg = blockIdx.x, tid = threadIdx.x;
  unsigned* line = bars + (wg & 7) * 64;
  unsigned* xcds = bars + 512;
  unsigned* hbar = bars + 768;

  // one-shot handshake (round-8 proven): slice on ONE XCD? -> z data via L2
  unsigned xcc;
  asm volatile("s_getreg_b32 %0, hwreg(HW_REG_XCC_ID)" : "=s"(xcc));
  if (tid == 0) {
    __hip_atomic_store(&xcds[wg], xcc + 1u, __ATOMIC_RELAXED, __HIP_MEMORY_SCOPE_AGENT);
    asm volatile("s_waitcnt vmcnt(0)" ::: "memory");
    __hip_atomic_fetch_add(hbar, 1u, __ATOMIC_RELAXED, __HIP_MEMORY_SCOPE_AGENT);
    while (__hip_atomic_load(hbar, __ATOMIC_RELAXED, __HIP_MEMORY_SCOPE_AGENT) < 256u)
      __builtin_amdgcn_s_sleep(1);
    const unsigned v0 = __hip_atomic_load(&xcds[wg & 7], __ATOMIC_RELAXED, __HIP_MEMORY_SCOPE_AGENT);
    unsigned m = 1u;
    for (int j = 1; j < 32; ++j)
      m &= (__hip_atomic_load(&xcds[(wg & 7) + 8 * j], __ATOMIC_RELAXED,
                              __HIP_MEMORY_SCOPE_AGENT) == v0) ? 1u : 0u;
    modeSh = m;
  }
  __syncthreads();

  if (modeSh)
    run_phases<true >(xs, Wh, bh, Wy, by, zT, out, line, P, wg, tid);
  else
    run_phases<false>(xs, Wh, bh, Wy, by, zT, out, line, P, wg, tid);
}

// ---------------- host launch ----------------
extern "C" void kernel_launch(void* const* d_in, const int* in_sizes, int n_in,
                              void* d_out, int out_size, void* d_ws, size_t ws_size,
                              hipStream_t stream) {
  (void)in_sizes; (void)n_in; (void)out_size; (void)ws_size;
  const float* xs  = (const float*)d_in[0];
  const float* W_h = (const float*)d_in[1];
  const float* b_h = (const float*)d_in[2];
  const float* W_y = (const float*)d_in[3];
  const float* b_y = (const float*)d_in[4];
  const float* h0  = (const float*)d_in[5];
  float* out = (float*)d_out;

  // ws layout: zT bf16 [4][256][1536] ring | bars/xcds/hbar (1024 u32)
  unsigned short* zT = (unsigned short*)d_ws;
  unsigned* bars = (unsigned*)(zT + 4 * (size_t)ZSZ);

  elman_setup<<<dim3(NB), dim3(256), 0, stream>>>(h0, xs, zT, bars);

  void* args[8];
  args[0] = (void*)&xs;  args[1] = (void*)&W_h; args[2] = (void*)&b_h;
  args[3] = (void*)&W_y; args[4] = (void*)&b_y; args[5] = (void*)&zT;
  args[6] = (void*)&out; args[7] = (void*)&bars;
  hipLaunchCooperativeKernel((void*)elman_seq, dim3(256), dim3(512), args, 0u, stream);
}

// Round 14
// 3669.895 us; speedup vs baseline: 1.1492x; 1.1492x over previous
//
#include <hip/hip_runtime.h>
#include <hip/hip_bf16.h>

#define T_STEPS 512
#define INP     512
#define NB      256
#define HID     1024
#define WID     512
#define KZ      1536   // HID + INP
#define ZSZ     (NB * KZ)

typedef short          bf16x8   __attribute__((ext_vector_type(8)));
typedef float          f32x4    __attribute__((ext_vector_type(4)));
typedef float          f32x2    __attribute__((ext_vector_type(2)));
typedef unsigned short ushort8  __attribute__((ext_vector_type(8)));
typedef unsigned short ushort2v __attribute__((ext_vector_type(2)));
typedef unsigned long long u64;

__device__ __forceinline__ unsigned short f2bf(float x) {
  __hip_bfloat16 h = __float2bfloat16(x);
  return __builtin_bit_cast(unsigned short, h);
}
__device__ __forceinline__ float sigm(float x) { return 1.0f / (1.0f + __expf(-x)); }

// ---- z ring access, two coherence modes (round-8 proven) ----
#define ZLOAD_FAST(dst, p) \
  asm volatile("global_load_dwordx4 %0, %1, off sc0" : "=v"(dst) : "v"(p))
#define ZLOAD_SLOW(dst, p) \
  asm volatile("global_load_dwordx4 %0, %1, off sc0 sc1" : "=v"(dst) : "v"(p))
#define ZWAIT() do { \
  asm volatile("s_waitcnt vmcnt(0)" ::: "memory"); \
  __builtin_amdgcn_sched_barrier(0); \
} while (0)

template <bool FAST>
__device__ __forceinline__ void zst4(unsigned short* p, ushort2v v) {
  if constexpr (FAST) *(unsigned*)p = __builtin_bit_cast(unsigned, v);
  else __hip_atomic_store((unsigned*)p, __builtin_bit_cast(unsigned, v),
                          __ATOMIC_RELAXED, __HIP_MEMORY_SCOPE_AGENT);
}

// ---- sync: ONE aggregated ticket per slice, agent-scope LLC (R8-proven) ----
// HARD RULE (hangs R5/R9): spin-polls at LLC scope; arrivals agent-scope RMW.
__device__ __forceinline__ void poll1(unsigned* p, unsigned tgt) {
  while (__hip_atomic_load(p, __ATOMIC_RELAXED, __HIP_MEMORY_SCOPE_AGENT) < tgt)
    __builtin_amdgcn_s_sleep(1);
}
__device__ __forceinline__ void arrive(unsigned* ctr) {
  asm volatile("s_waitcnt vmcnt(0)" ::: "memory");   // my z/out stores committed
  __syncthreads();                                   // whole WG drained
  if (threadIdx.x == 0)
    __hip_atomic_fetch_add(ctr, 1u, __ATOMIC_RELAXED, __HIP_MEMORY_SCOPE_AGENT);
}

// ---------------- setup: z ring init (z_0 full, x_1 part), zero sync area ----------------
__global__ void elman_setup(const float* __restrict__ h0, const float* __restrict__ xs,
                            unsigned short* __restrict__ zT, unsigned* __restrict__ bars) {
  const int b = blockIdx.x;
  if (b == 0) {
    for (int j = threadIdx.x; j < 1024; j += blockDim.x) bars[j] = 0u;
  }
  for (int k = threadIdx.x; k < KZ; k += blockDim.x) {   // buf0 = z_0
    const float v = (k < HID) ? h0[k] : xs[(size_t)(k - HID) * NB + b];
    zT[(size_t)b * KZ + k] = f2bf(v);
  }
  for (int i = threadIdx.x; i < INP; i += blockDim.x)    // buf1 x-part = x_1
    zT[(size_t)ZSZ + (size_t)b * KZ + HID + i] = f2bf(xs[(size_t)(INP + i) * NB + b]);
}

// LDS: h region 8 waves x [32 cols][stride 36] + y region same = 72 KiB total
#define PSTR 36
#define PWSZ (32 * PSTR)

// ---------------- merged phase loop ----------------
// 128 WGs x 512 threads, slice = wg & 7 (16 WGs, ONE role each covering h+y+x).
// Iteration t (t = 0..T+1):
//   y: out[t-2] <- sigm(Wy[m0y..+32) @ z_{t-1}.h)   (t>=2)   [reads rows <1024]
//   x: z_{t+2}.x rows [i0x..+32) <- xs[t+2]         (t<=T-3) [writes rows >=1024]
//   poll: ticket >= 16t (single condition)          (1<=t<=T)
//   h: z_{t+1}.h rows [m0h..+64) <- sigm(Wh @ z_t)  (t<T)
//   arrive: ticket += 1
// Certification (induction):
//  - y@t reads z_{t-1}.h (h@t-2 output): certified by poll@t-1 (completed t-2).
//  - h@t reads z_t (h-part h@t-1, x-part x@t-2): certified by poll@t.
//  - ring buf (t-1)&3 h-part rewritten first by h@t+2 (needs poll@t+2, which
//    includes completion of iteration t => y@t done).  x writes are row-disjoint
//    from all y/h-part readers.  x@t writes buf (t+2)&3 x-part (z_{t-2}.x): all
//    h@t-2 readers certified done by poll@t-1.  z_T.x never needed (y reads h only).
template <bool FAST>
__device__ __forceinline__ void run_phases(
    const float* __restrict__ xs,
    const float* __restrict__ Wh, const float* __restrict__ bh,
    const float* __restrict__ Wy, const float* __restrict__ by,
    unsigned short* __restrict__ zT, float* __restrict__ out,
    unsigned* line, float* P, int wg, int tid) {
  const int w = tid >> 6, lane = tid & 63;
  const int lr = lane & 15, lk = lane >> 4;
  const int m0h = (wg >> 3) * 64;     // h output rows
  const int m0y = (wg >> 3) * 32;     // y output rows
  const int i0x = (wg >> 3) * 32;     // x input-feature rows
  const int n0  = (wg & 7) * 32;      // slice batch columns
  const int kwh = w * 192;            // h K-slice (6 kc)
  const int kwy = w * 128;            // y K-slice (4 kc)

  // resident W_h fragments: 96 VGPRs
  bf16x8 Ah[4][6];
#pragma unroll
  for (int mt = 0; mt < 4; ++mt)
#pragma unroll
    for (int kc = 0; kc < 6; ++kc) {
      const float* wp = Wh + (size_t)(m0h + mt * 16 + lr) * KZ + kwh + kc * 32 + lk * 8;
      const f32x4 f0 = *(const f32x4*)wp;
      const f32x4 f1 = *(const f32x4*)(wp + 4);
      ushort8 a;
#pragma unroll
      for (int e = 0; e < 4; ++e) { a[e] = f2bf(f0[e]); a[4 + e] = f2bf(f1[e]); }
      Ah[mt][kc] = __builtin_bit_cast(bf16x8, a);
    }
  // resident W_y fragments: 32 VGPRs
  bf16x8 Ay[2][4];
#pragma unroll
  for (int mt = 0; mt < 2; ++mt)
#pragma unroll
    for (int kc = 0; kc < 4; ++kc) {
      const float* wp = Wy + (size_t)(m0y + mt * 16 + lr) * HID + kwy + kc * 32 + lk * 8;
      const f32x4 f0 = *(const f32x4*)wp;
      const f32x4 f1 = *(const f32x4*)(wp + 4);
      ushort8 a;
#pragma unroll
      for (int e = 0; e < 4; ++e) { a[e] = f2bf(f0[e]); a[4 + e] = f2bf(f1[e]); }
      Ay[mt][kc] = __builtin_bit_cast(bf16x8, a);
    }

  const int lcolh = tid >> 4, r2h = (tid & 15) * 2;   // h reduce roles
  const int lcoly = tid & 31, r2y = (tid >> 5) * 2;   // y reduce roles (coalesced out)
  const int cx = tid & 31,  rx = (tid >> 5) * 2;      // x roles
  f32x2 biasH[2];
#pragma unroll
  for (int hf = 0; hf < 2; ++hf) biasH[hf] = *(const f32x2*)&bh[m0h + hf * 32 + r2h];
  const f32x2 biasY = *(const f32x2*)&by[m0y + r2y];
  float* Ph = P;                 // 8*PWSZ
  float* Py = P + 8 * PWSZ;      // 8*PWSZ
  float* PwH = Ph + w * PWSZ;
  float* PwY = Py + w * PWSZ;

  for (int t = 0; t <= T_STEPS + 1; ++t) {
    // ---- issue x HBM loads first (latency hides under y-MFMA) ----
    float xv0 = 0.f, xv1 = 0.f;
    if (t <= T_STEPS - 3) {
      const float* xp = xs + (size_t)(t + 2) * (INP * NB) + (size_t)(i0x + rx) * NB + n0 + cx;
      xv0 = xp[0];
      xv1 = xp[NB];
    }
    // ---- y: out[t-2] from z_{t-1}.h (certified by poll@t-1) ----
    if (t >= 2) {
      const unsigned short* zb = zT + (size_t)((t - 1) & 3) * ZSZ + (size_t)(n0 + lr) * KZ + kwy + lk * 8;
      bf16x8 fb[4][2];
#pragma unroll
      for (int kc = 0; kc < 4; ++kc)
#pragma unroll
        for (int nt = 0; nt < 2; ++nt) {
          if constexpr (FAST) ZLOAD_FAST(fb[kc][nt], zb + nt * (16 * KZ) + kc * 32);
          else                ZLOAD_SLOW(fb[kc][nt], zb + nt * (16 * KZ) + kc * 32);
        }
      ZWAIT();
      f32x4 ay[2][2];
#pragma unroll
      for (int mt = 0; mt < 2; ++mt)
#pragma unroll
        for (int nt = 0; nt < 2; ++nt) ay[mt][nt] = (f32x4){0.f, 0.f, 0.f, 0.f};
#pragma unroll
      for (int kc = 0; kc < 4; ++kc)
#pragma unroll
        for (int nt = 0; nt < 2; ++nt)
#pragma unroll
          for (int mt = 0; mt < 2; ++mt)
            ay[mt][nt] = __builtin_amdgcn_mfma_f32_16x16x32_bf16(Ay[mt][kc], fb[kc][nt], ay[mt][nt], 0, 0, 0);
#pragma unroll
      for (int mt = 0; mt < 2; ++mt)
#pragma unroll
        for (int nt = 0; nt < 2; ++nt)
          *(f32x4*)&PwY[(nt * 16 + lr) * PSTR + mt * 16 + lk * 4] = ay[mt][nt];
      __syncthreads();
      f32x2 s = {0.f, 0.f};
#pragma unroll
      for (int ww = 0; ww < 8; ++ww)
        s += *(const f32x2*)&Py[ww * PWSZ + lcoly * PSTR + r2y];
      s += biasY;
      float* op = out + (size_t)(t - 2) * (WID * NB);
      op[(size_t)(m0y + r2y + 0) * NB + n0 + lcoly] = sigm(s[0]);
      op[(size_t)(m0y + r2y + 1) * NB + n0 + lcoly] = sigm(s[1]);
    }
    // ---- x: convert + store into z_{t+2}.x ----
    if (t <= T_STEPS - 3) {
      ushort2v o;
      o[0] = f2bf(xv0);
      o[1] = f2bf(xv1);
      zst4<FAST>(zT + (size_t)((t + 2) & 3) * ZSZ + (size_t)(n0 + cx) * KZ + HID + i0x + rx, o);
    }
    // ---- single-condition poll: all WGs completed phase t-1 => z_t ready ----
    if (t >= 1 && t <= T_STEPS) {
      if (tid == 0) poll1(line, 16u * (unsigned)t);
      __syncthreads();
    }
    // ---- h: z_{t+1} from z_t (R8 structure) ----
    if (t < T_STEPS) {
      const unsigned short* zc = zT + (size_t)(t & 3) * ZSZ;
      unsigned short* zn = zT + (size_t)((t + 1) & 3) * ZSZ;
      const unsigned short* zb = zc + (size_t)(n0 + lr) * KZ + kwh + lk * 8;
      bf16x8 bfr[6][2];
#pragma unroll
      for (int kc = 0; kc < 6; ++kc)
#pragma unroll
        for (int nt = 0; nt < 2; ++nt) {
          if constexpr (FAST) ZLOAD_FAST(bfr[kc][nt], zb + nt * (16 * KZ) + kc * 32);
          else                ZLOAD_SLOW(bfr[kc][nt], zb + nt * (16 * KZ) + kc * 32);
        }
      ZWAIT();
      f32x4 acc[4][2];
#pragma unroll
      for (int mt = 0; mt < 4; ++mt)
#pragma unroll
        for (int nt = 0; nt < 2; ++nt) acc[mt][nt] = (f32x4){0.f, 0.f, 0.f, 0.f};
#pragma unroll
      for (int kc = 0; kc < 6; ++kc)
#pragma unroll
        for (int nt = 0; nt < 2; ++nt)
#pragma unroll
          for (int mt = 0; mt < 4; ++mt)
            acc[mt][nt] = __builtin_amdgcn_mfma_f32_16x16x32_bf16(Ah[mt][kc], bfr[kc][nt], acc[mt][nt], 0, 0, 0);
      // two-pass cross-wave K reduction (R8 verbatim, region Ph)
#pragma unroll
      for (int hf = 0; hf < 2; ++hf) {
#pragma unroll
        for (int mp = 0; mp < 2; ++mp) {
          const int mt = hf * 2 + mp;
#pragma unroll
          for (int nt = 0; nt < 2; ++nt)
            *(f32x4*)&PwH[(nt * 16 + lr) * PSTR + mp * 16 + lk * 4] = acc[mt][nt];
        }
        __syncthreads();
        f32x2 s = {0.f, 0.f};
#pragma unroll
        for (int ww = 0; ww < 8; ++ww)
          s += *(const f32x2*)&Ph[ww * PWSZ + lcolh * PSTR + r2h];
        s += biasH[hf];
        ushort2v o2;
        o2[0] = f2bf(sigm(s[0]));
        o2[1] = f2bf(sigm(s[1]));
        zst4<FAST>(zn + (size_t)(n0 + lcolh) * KZ + m0h + hf * 32 + r2h, o2);
        if (hf == 0) __syncthreads();
      }
    }
    arrive(line);
  }
}

// ---------------- persistent sequential kernel ----------------
__global__ void __launch_bounds__(512, 1) elman_seq(
    const float* __restrict__ xs,
    const float* __restrict__ Wh, const float* __restrict__ bh,
    const float* __restrict__ Wy, const float* __restrict__ by,
    unsigned short* __restrict__ zT, float* __restrict__ out,
    unsigned* __restrict__ bars) {
  __shared__ float P[16 * PWSZ];   // 72 KiB
  __shared__ unsigned modeSh;
  const int wg = blockIdx.x, tid = threadIdx.x;
  unsigned* line = bars + (wg & 7) * 64;   // one ticket word per slice
  unsigned* xcds = bars + 512;
  unsigned* hbar = bars + 768;

  // one-shot handshake (R8-proven): slice on ONE XCD? -> z data via L2
  unsigned xcc;
  asm volatile("s_getreg_b32 %0, hwreg(HW_REG_XCC_ID)" : "=s"(xcc));
  if (tid == 0) {
    __hip_atomic_store(&xcds[wg], xcc + 1u, __ATOMIC_RELAXED, __HIP_MEMORY_SCOPE_AGENT);
    asm volatile("s_waitcnt vmcnt(0)" ::: "memory");
    __hip_atomic_fetch_add(hbar, 1u, __ATOMIC_RELAXED, __HIP_MEMORY_SCOPE_AGENT);
    while (__hip_atomic_load(hbar, __ATOMIC_RELAXED, __HIP_MEMORY_SCOPE_AGENT) < 128u)
      __builtin_amdgcn_s_sleep(1);
    const unsigned v0 = __hip_atomic_load(&xcds[wg & 7], __ATOMIC_RELAXED, __HIP_MEMORY_SCOPE_AGENT);
    unsigned m = 1u;
    for (int j = 1; j < 16; ++j)
      m &= (__hip_atomic_load(&xcds[(wg & 7) + 8 * j], __ATOMIC_RELAXED,
                              __HIP_MEMORY_SCOPE_AGENT) == v0) ? 1u : 0u;
    modeSh = m;
  }
  __syncthreads();

  if (modeSh)
    run_phases<true >(xs, Wh, bh, Wy, by, zT, out, line, P, wg, tid);
  else
    run_phases<false>(xs, Wh, bh, Wy, by, zT, out, line, P, wg, tid);
}

// ---------------- host launch ----------------
extern "C" void kernel_launch(void* const* d_in, const int* in_sizes, int n_in,
                              void* d_out, int out_size, void* d_ws, size_t ws_size,
                              hipStream_t stream) {
  (void)in_sizes; (void)n_in; (void)out_size; (void)ws_size;
  const float* xs  = (const float*)d_in[0];
  const float* W_h = (const float*)d_in[1];
  const float* b_h = (const float*)d_in[2];
  const float* W_y = (const float*)d_in[3];
  const float* b_y = (const float*)d_in[4];
  const float* h0  = (const float*)d_in[5];
  float* out = (float*)d_out;

  // ws layout: zT bf16 [4][256][1536] ring | bars/xcds/hbar (1024 u32)
  unsigned short* zT = (unsigned short*)d_ws;
  unsigned* bars = (unsigned*)(zT + 4 * (size_t)ZSZ);

  elman_setup<<<dim3(NB), dim3(256), 0, stream>>>(h0, xs, zT, bars);

  void* args[8];
  args[0] = (void*)&xs;  args[1] = (void*)&W_h; args[2] = (void*)&b_h;
  args[3] = (void*)&W_y; args[4] = (void*)&b_y; args[5] = (void*)&zT;
  args[6] = (void*)&out; args[7] = (void*)&bars;
  hipLaunchCooperativeKernel((void*)elman_seq, dim3(128), dim3(512), args, 0u, stream);
}

// Round 15
// 3506.544 us; speedup vs baseline: 1.2027x; 1.0466x over previous
//
#include <hip/hip_runtime.h>
#include <hip/hip_bf16.h>

#define T_STEPS 512
#define INP     512
#define NB      256
#define HID     1024
#define WID     512
#define KZ      1536   // HID + INP
#define ZSZ     (NB * KZ)

typedef short          bf16x8   __attribute__((ext_vector_type(8)));
typedef float          f32x4    __attribute__((ext_vector_type(4)));
typedef float          f32x2    __attribute__((ext_vector_type(2)));
typedef unsigned short ushort8  __attribute__((ext_vector_type(8)));
typedef unsigned short ushort2v __attribute__((ext_vector_type(2)));
typedef unsigned short ushort4v __attribute__((ext_vector_type(4)));
typedef unsigned       uint4v   __attribute__((ext_vector_type(4)));
typedef unsigned long long u64;

__device__ __forceinline__ unsigned short f2bf(float x) {
  __hip_bfloat16 h = __float2bfloat16(x);
  return __builtin_bit_cast(unsigned short, h);
}
__device__ __forceinline__ float sigm(float x) { return 1.0f / (1.0f + __expf(-x)); }

// ---- z ring access, two coherence modes (round-8 proven) ----
#define ZLOAD_FAST(dst, p) \
  asm volatile("global_load_dwordx4 %0, %1, off sc0" : "=v"(dst) : "v"(p))
#define ZLOAD_SLOW(dst, p) \
  asm volatile("global_load_dwordx4 %0, %1, off sc0 sc1" : "=v"(dst) : "v"(p))
#define ZWAIT() do { \
  asm volatile("s_waitcnt vmcnt(0)" ::: "memory"); \
  __builtin_amdgcn_sched_barrier(0); \
} while (0)

template <bool FAST>
__device__ __forceinline__ void zst4(unsigned short* p, ushort2v v) {
  if constexpr (FAST) *(unsigned*)p = __builtin_bit_cast(unsigned, v);
  else __hip_atomic_store((unsigned*)p, __builtin_bit_cast(unsigned, v),
                          __ATOMIC_RELAXED, __HIP_MEMORY_SCOPE_AGENT);
}
template <bool FAST>
__device__ __forceinline__ void zst8(unsigned short* p, ushort4v v) {
  if constexpr (FAST) *(u64*)p = __builtin_bit_cast(u64, v);
  else __hip_atomic_store((u64*)p, __builtin_bit_cast(u64, v),
                          __ATOMIC_RELAXED, __HIP_MEMORY_SCOPE_AGENT);
}

// ---- sync: LLC (sc0|sc1) spin-polls, contention-spread layout ----
// HARD RULES (hangs R5/R9): polls at LLC scope; all primitives below are
// proven shapes (R8 poll1/fetch_add; R12 slot-store + 4xSLD4 gate, which PASSED).
// Per-slice region (256 u32 words = 4 cachelines):
//   words [0..15]   : h per-WG arrival slots (atomic_store, distinct words - no RMW)
//   word  [64]      : x aggregated ticket (fetch_add, own line)
//   word  [128]     : y aggregated ticket (fetch_add, own line)
#define SLD4(dst, p) \
  asm volatile("global_load_dwordx4 %0, %1, off sc0 sc1" : "=v"(dst) : "v"(p))
#define SLD1(dst, p) \
  asm volatile("global_load_dword %0, %1, off sc0 sc1" : "=v"(dst) : "v"(p))
#define SWAITM() asm volatile("s_waitcnt vmcnt(0)" ::: "memory")

__device__ __forceinline__ bool all16_ge(const uint4v& a, const uint4v& b,
                                         const uint4v& c, const uint4v& d, unsigned t) {
  return a.x >= t && a.y >= t && a.z >= t && a.w >= t &&
         b.x >= t && b.y >= t && b.z >= t && b.w >= t &&
         c.x >= t && c.y >= t && c.z >= t && c.w >= t &&
         d.x >= t && d.y >= t && d.z >= t && d.w >= t;
}
// h poll: all 16 h slots >= ht, x ticket >= xt, y ticket >= yt
__device__ __forceinline__ void poll_h(const unsigned* sl, unsigned ht, unsigned xt, unsigned yt) {
  for (;;) {
    uint4v a, b, c, d; unsigned xv, yv;
    SLD4(a, sl); SLD4(b, sl + 4); SLD4(c, sl + 8); SLD4(d, sl + 12);
    SLD1(xv, sl + 64); SLD1(yv, sl + 128);
    SWAITM();
    if (all16_ge(a, b, c, d, ht) && xv >= xt && yv >= yt) return;
    __builtin_amdgcn_s_sleep(1);
  }
}
// y/x poll: all 16 h slots >= t
__device__ __forceinline__ void poll_hs(const unsigned* sl, unsigned t) {
  for (;;) {
    uint4v a, b, c, d;
    SLD4(a, sl); SLD4(b, sl + 4); SLD4(c, sl + 8); SLD4(d, sl + 12);
    SWAITM();
    if (all16_ge(a, b, c, d, t)) return;
    __builtin_amdgcn_s_sleep(1);
  }
}
// h arrival: per-WG slot store (no RMW); x/y arrival: fetch_add on own line
__device__ __forceinline__ void arrive_store(unsigned* slot, unsigned val) {
  asm volatile("s_waitcnt vmcnt(0)" ::: "memory");   // my z stores committed
  __syncthreads();                                   // whole WG drained
  if (threadIdx.x == 0)
    __hip_atomic_store(slot, val, __ATOMIC_RELAXED, __HIP_MEMORY_SCOPE_AGENT);
}
__device__ __forceinline__ void arrive_add(unsigned* ctr) {
  asm volatile("s_waitcnt vmcnt(0)" ::: "memory");
  __syncthreads();
  if (threadIdx.x == 0)
    __hip_atomic_fetch_add(ctr, 1u, __ATOMIC_RELAXED, __HIP_MEMORY_SCOPE_AGENT);
}

// ---------------- setup: z ring init (z_0 full, x_1 part), zero sync area ----------------
__global__ void elman_setup(const float* __restrict__ h0, const float* __restrict__ xs,
                            unsigned short* __restrict__ zT, unsigned* __restrict__ bars) {
  const int b = blockIdx.x;
  if (b == 0) {
    for (int j = threadIdx.x; j < 2560; j += blockDim.x) bars[j] = 0u;
  }
  for (int k = threadIdx.x; k < KZ; k += blockDim.x) {   // buf0 = z_0
    const float v = (k < HID) ? h0[k] : xs[(size_t)(k - HID) * NB + b];
    zT[(size_t)b * KZ + k] = f2bf(v);
  }
  for (int i = threadIdx.x; i < INP; i += blockDim.x)    // buf1 x-part = x_1
    zT[(size_t)ZSZ + (size_t)b * KZ + HID + i] = f2bf(xs[(size_t)(INP + i) * NB + b]);
}

// LDS partial-sum buffer: 8 waves x [32 cols][stride 36 words]
#define PSTR 36
#define PWSZ (32 * PSTR)

// ---------------- phase loop (R8 compute bodies, detoxed sync) ----------------
// 256 WGs x 512 threads. slice = wg & 7 (32 WGs: 16 h + 8 y + 8 x), 4-deep z ring.
// Phase t:  h: z_{t+1}.h <- sigm(Wh @ z_t)   poll: slots>=t, x>=8(t-1), y>=8(t-2)
//           y: out[t-1] <- sigm(Wy @ z_t.h)  poll: slots>=t               (t>=1)
//           x: z_{t+2}.x <- xs[t+2]          poll: slots>=t-1             (t<=T-3)
template <bool FAST>
__device__ __forceinline__ void run_phases(
    const float* __restrict__ xs,
    const float* __restrict__ Wh, const float* __restrict__ bh,
    const float* __restrict__ Wy, const float* __restrict__ by,
    unsigned short* __restrict__ zT, float* __restrict__ out,
    unsigned* line, float* P, int wg, int tid) {
  const int w = tid >> 6, lane = tid & 63;
  const int lr = lane & 15, lk = lane >> 4;

  if (wg < 128) {
    // ================= h role =================
    const int m0 = (wg >> 3) * 64;
    const int n0 = (wg & 7) * 32;
    const int kw = w * 192;
    unsigned* slot = line + (wg >> 3);
    bf16x8 A[4][6];                         // resident W_h fragments
#pragma unroll
    for (int mt = 0; mt < 4; ++mt)
#pragma unroll
      for (int kc = 0; kc < 6; ++kc) {
        const float* wp = Wh + (size_t)(m0 + mt * 16 + lr) * KZ + kw + kc * 32 + lk * 8;
        const f32x4 f0 = *(const f32x4*)wp;
        const f32x4 f1 = *(const f32x4*)(wp + 4);
        ushort8 a;
#pragma unroll
        for (int e = 0; e < 4; ++e) { a[e] = f2bf(f0[e]); a[4 + e] = f2bf(f1[e]); }
        A[mt][kc] = __builtin_bit_cast(bf16x8, a);
      }
    const int lcol = tid >> 4;
    const int r2 = (tid & 15) * 2;
    f32x2 bias[2];
#pragma unroll
    for (int hf = 0; hf < 2; ++hf) bias[hf] = *(const f32x2*)&bh[m0 + hf * 32 + r2];
    float* Pw = P + w * PWSZ;

    for (int t = 0; t <= T_STEPS; ++t) {
      if (t < T_STEPS) {
        const unsigned short* zc = zT + (size_t)(t & 3) * ZSZ;
        unsigned short* zn = zT + (size_t)((t + 1) & 3) * ZSZ;
        if (t >= 1) {
          if (tid == 0) poll_h(line, (unsigned)t, 8u * (unsigned)(t - 1),
                               (t >= 2) ? 8u * (unsigned)(t - 2) : 0u);
          __syncthreads();
        }
        const unsigned short* zb = zc + (size_t)(n0 + lr) * KZ + kw + lk * 8;
        bf16x8 bfr[6][2];
#pragma unroll
        for (int kc = 0; kc < 6; ++kc)
#pragma unroll
          for (int nt = 0; nt < 2; ++nt) {
            if constexpr (FAST) ZLOAD_FAST(bfr[kc][nt], zb + nt * (16 * KZ) + kc * 32);
            else                ZLOAD_SLOW(bfr[kc][nt], zb + nt * (16 * KZ) + kc * 32);
          }
        ZWAIT();
        f32x4 acc[4][2];
#pragma unroll
        for (int mt = 0; mt < 4; ++mt)
#pragma unroll
          for (int nt = 0; nt < 2; ++nt) acc[mt][nt] = (f32x4){0.f, 0.f, 0.f, 0.f};
#pragma unroll
        for (int kc = 0; kc < 6; ++kc)
#pragma unroll
          for (int nt = 0; nt < 2; ++nt)
#pragma unroll
            for (int mt = 0; mt < 4; ++mt)
              acc[mt][nt] = __builtin_amdgcn_mfma_f32_16x16x32_bf16(A[mt][kc], bfr[kc][nt], acc[mt][nt], 0, 0, 0);
        __syncthreads();   // previous phase's P reads complete before overwrite
        // two-pass cross-wave K reduction through LDS
#pragma unroll
        for (int hf = 0; hf < 2; ++hf) {
#pragma unroll
          for (int mp = 0; mp < 2; ++mp) {
            const int mt = hf * 2 + mp;
#pragma unroll
            for (int nt = 0; nt < 2; ++nt)
              *(f32x4*)&Pw[(nt * 16 + lr) * PSTR + mp * 16 + lk * 4] = acc[mt][nt];
          }
          __syncthreads();
          f32x2 s = {0.f, 0.f};
#pragma unroll
          for (int ww = 0; ww < 8; ++ww)
            s += *(const f32x2*)&P[ww * PWSZ + lcol * PSTR + r2];
          s += bias[hf];
          ushort2v o2;
          o2[0] = f2bf(sigm(s[0]));
          o2[1] = f2bf(sigm(s[1]));
          zst4<FAST>(zn + (size_t)(n0 + lcol) * KZ + m0 + hf * 32 + r2, o2);
          if (hf == 0) __syncthreads();
        }
      }
      arrive_store(slot, (unsigned)(t + 1));
    }

  } else if (wg < 192) {
    // ================= y role =================
    const int idx = wg - 128;
    const int m0 = (idx >> 3) * 64;
    const int n0 = (idx & 7) * 32;
    const int kw = w * 128;
    bf16x8 A[4][4];                         // resident W_y fragments
#pragma unroll
    for (int mt = 0; mt < 4; ++mt)
#pragma unroll
      for (int kc = 0; kc < 4; ++kc) {
        const float* wp = Wy + (size_t)(m0 + mt * 16 + lr) * HID + kw + kc * 32 + lk * 8;
        const f32x4 f0 = *(const f32x4*)wp;
        const f32x4 f1 = *(const f32x4*)(wp + 4);
        ushort8 a;
#pragma unroll
        for (int e = 0; e < 4; ++e) { a[e] = f2bf(f0[e]); a[4 + e] = f2bf(f1[e]); }
        A[mt][kc] = __builtin_bit_cast(bf16x8, a);
      }
    const int lcol = tid & 31;
    const int r2 = (tid >> 5) * 2;
    f32x2 bias[2];
#pragma unroll
    for (int hf = 0; hf < 2; ++hf) bias[hf] = *(const f32x2*)&by[m0 + hf * 32 + r2];
    float* Pw = P + w * PWSZ;

    for (int t = 0; t <= T_STEPS; ++t) {
      if (t >= 1) {
        const unsigned short* zc = zT + (size_t)(t & 3) * ZSZ;
        if (tid == 0) poll_hs(line, (unsigned)t);
        __syncthreads();
        const unsigned short* zb = zc + (size_t)(n0 + lr) * KZ + kw + lk * 8;
        bf16x8 bfr[4][2];
#pragma unroll
        for (int kc = 0; kc < 4; ++kc)
#pragma unroll
          for (int nt = 0; nt < 2; ++nt) {
            if constexpr (FAST) ZLOAD_FAST(bfr[kc][nt], zb + nt * (16 * KZ) + kc * 32);
            else                ZLOAD_SLOW(bfr[kc][nt], zb + nt * (16 * KZ) + kc * 32);
          }
        ZWAIT();
        f32x4 acc[4][2];
#pragma unroll
        for (int mt = 0; mt < 4; ++mt)
#pragma unroll
          for (int nt = 0; nt < 2; ++nt) acc[mt][nt] = (f32x4){0.f, 0.f, 0.f, 0.f};
#pragma unroll
        for (int kc = 0; kc < 4; ++kc)
#pragma unroll
          for (int nt = 0; nt < 2; ++nt)
#pragma unroll
            for (int mt = 0; mt < 4; ++mt)
              acc[mt][nt] = __builtin_amdgcn_mfma_f32_16x16x32_bf16(A[mt][kc], bfr[kc][nt], acc[mt][nt], 0, 0, 0);
        float* op = out + (size_t)(t - 1) * (WID * NB);
        __syncthreads();
#pragma unroll
        for (int hf = 0; hf < 2; ++hf) {
#pragma unroll
          for (int mp = 0; mp < 2; ++mp) {
            const int mt = hf * 2 + mp;
#pragma unroll
            for (int nt = 0; nt < 2; ++nt)
              *(f32x4*)&Pw[(nt * 16 + lr) * PSTR + mp * 16 + lk * 4] = acc[mt][nt];
          }
          __syncthreads();
          f32x2 s = {0.f, 0.f};
#pragma unroll
          for (int ww = 0; ww < 8; ++ww)
            s += *(const f32x2*)&P[ww * PWSZ + lcol * PSTR + r2];
          s += bias[hf];
          const int row = m0 + hf * 32 + r2;
          op[(size_t)(row + 0) * NB + n0 + lcol] = sigm(s[0]);  // cached; flushed at kernel end
          op[(size_t)(row + 1) * NB + n0 + lcol] = sigm(s[1]);
          if (hf == 0) __syncthreads();
        }
      }
      arrive_add(line + 128);
    }

  } else {
    // ================= x role (one phase ahead: writes x_{t+2}) =================
    const int xi = wg - 192;
    const int i0 = (xi >> 3) * 64;
    const int b0 = (xi & 7) * 32;
    const int c = tid & 31, rb = tid >> 5;
    for (int t = 0; t <= T_STEPS; ++t) {
      if (t <= T_STEPS - 3) {
        unsigned short* zx = zT + (size_t)((t + 2) & 3) * ZSZ;
        const float* xp = xs + (size_t)(t + 2) * (INP * NB) + (size_t)(i0 + rb * 4) * NB + b0 + c;
        ushort4v o;
#pragma unroll
        for (int j = 0; j < 4; ++j) o[j] = f2bf(xp[(size_t)j * NB]);
        if (t >= 2 && tid == 0) poll_hs(line, (unsigned)(t - 1));
        __syncthreads();
        zst8<FAST>(zx + (size_t)(b0 + c) * KZ + HID + i0 + rb * 4, o);
      }
      arrive_add(line + 64);
    }
  }
}

// ---------------- persistent sequential kernel ----------------
__global__ void __launch_bounds__(512, 2) elman_seq(
    const float* __restrict__ xs,
    const float* __restrict__ Wh, const float* __restrict__ bh,
    const float* __restrict__ Wy, const float* __restrict__ by,
    unsigned short* __restrict__ zT, float* __restrict__ out,
    unsigned* __restrict__ bars) {
  __shared__ float P[8 * PWSZ];
  __shared__ unsigned modeSh;
  const int wg = blockIdx.x, tid = threadIdx.x;
  unsigned* line = bars + (wg & 7) * 256;   // 4-cacheline sync region per slice
  unsigned* xcds = bars + 2048;
  unsigned* hbar = bars + 2304;

  // one-shot handshake (R8-proven): slice on ONE XCD? -> z data via L2
  unsigned xcc;
  asm volatile("s_getreg_b32 %0, hwreg(HW_REG_XCC_ID)" : "=s"(xcc));
  if (tid == 0) {
    __hip_atomic_store(&xcds[wg], xcc + 1u, __ATOMIC_RELAXED, __HIP_MEMORY_SCOPE_AGENT);
    asm volatile("s_waitcnt vmcnt(0)" ::: "memory");
    __hip_atomic_fetch_add(hbar, 1u, __ATOMIC_RELAXED, __HIP_MEMORY_SCOPE_AGENT);
    while (__hip_atomic_load(hbar, __ATOMIC_RELAXED, __HIP_MEMORY_SCOPE_AGENT) < 256u)
      __builtin_amdgcn_s_sleep(1);
    const unsigned v0 = __hip_atomic_load(&xcds[wg & 7], __ATOMIC_RELAXED, __HIP_MEMORY_SCOPE_AGENT);
    unsigned m = 1u;
    for (int j = 1; j < 32; ++j)
      m &= (__hip_atomic_load(&xcds[(wg & 7) + 8 * j], __ATOMIC_RELAXED,
                              __HIP_MEMORY_SCOPE_AGENT) == v0) ? 1u : 0u;
    modeSh = m;
  }
  __syncthreads();

  if (modeSh)
    run_phases<true >(xs, Wh, bh, Wy, by, zT, out, line, P, wg, tid);
  else
    run_phases<false>(xs, Wh, bh, Wy, by, zT, out, line, P, wg, tid);
}

// ---------------- host launch ----------------
extern "C" void kernel_launch(void* const* d_in, const int* in_sizes, int n_in,
                              void* d_out, int out_size, void* d_ws, size_t ws_size,
                              hipStream_t stream) {
  (void)in_sizes; (void)n_in; (void)out_size; (void)ws_size;
  const float* xs  = (const float*)d_in[0];
  const float* W_h = (const float*)d_in[1];
  const float* b_h = (const float*)d_in[2];
  const float* W_y = (const float*)d_in[3];
  const float* b_y = (const float*)d_in[4];
  const float* h0  = (const float*)d_in[5];
  float* out = (float*)d_out;

  // ws layout: zT bf16 [4][256][1536] ring | bars/xcds/hbar (2560 u32)
  unsigned short* zT = (unsigned short*)d_ws;
  unsigned* bars = (unsigned*)(zT + 4 * (size_t)ZSZ);

  elman_setup<<<dim3(NB), dim3(256), 0, stream>>>(h0, xs, zT, bars);

  void* args[8];
  args[0] = (void*)&xs;  args[1] = (void*)&W_h; args[2] = (void*)&b_h;
  args[3] = (void*)&W_y; args[4] = (void*)&b_y; args[5] = (void*)&zT;
  args[6] = (void*)&out; args[7] = (void*)&bars;
  hipLaunchCooperativeKernel((void*)elman_seq, dim3(256), dim3(512), args, 0u, stream);
}

// Round 16
// 2607.722 us; speedup vs baseline: 1.6173x; 1.3447x over previous
//
#include <hip/hip_runtime.h>
#include <hip/hip_bf16.h>

#define T_STEPS 512
#define INP     512
#define NB      256
#define HID     1024
#define WID     512
#define KZ      1536   // HID + INP
#define ZSZ     (NB * KZ)
#define ZR      6      // ring depth

typedef short          bf16x8   __attribute__((ext_vector_type(8)));
typedef float          f32x4    __attribute__((ext_vector_type(4)));
typedef float          f32x2    __attribute__((ext_vector_type(2)));
typedef unsigned short ushort8  __attribute__((ext_vector_type(8)));
typedef unsigned short ushort2v __attribute__((ext_vector_type(2)));
typedef unsigned short ushort4v __attribute__((ext_vector_type(4)));
typedef unsigned       uint4v   __attribute__((ext_vector_type(4)));
typedef unsigned long long u64;

__device__ __forceinline__ unsigned short f2bf(float x) {
  __hip_bfloat16 h = __float2bfloat16(x);
  return __builtin_bit_cast(unsigned short, h);
}
__device__ __forceinline__ float sigm(float x) { return 1.0f / (1.0f + __expf(-x)); }

// ---- z ring access, two coherence modes (round-8 proven) ----
#define ZLOAD_FAST(dst, p) \
  asm volatile("global_load_dwordx4 %0, %1, off sc0" : "=v"(dst) : "v"(p))
#define ZLOAD_SLOW(dst, p) \
  asm volatile("global_load_dwordx4 %0, %1, off sc0 sc1" : "=v"(dst) : "v"(p))
// counted wait (T4-lite): N loads may stay in flight; sched_barrier pins MFMAs after (rule 18)
#define ZWAITN(n) do { \
  asm volatile("s_waitcnt vmcnt(" #n ")" ::: "memory"); \
  __builtin_amdgcn_sched_barrier(0); \
} while (0)

template <bool FAST>
__device__ __forceinline__ void zst4(unsigned short* p, ushort2v v) {
  if constexpr (FAST) *(unsigned*)p = __builtin_bit_cast(unsigned, v);
  else __hip_atomic_store((unsigned*)p, __builtin_bit_cast(unsigned, v),
                          __ATOMIC_RELAXED, __HIP_MEMORY_SCOPE_AGENT);
}
template <bool FAST>
__device__ __forceinline__ void zst8(unsigned short* p, ushort4v v) {
  if constexpr (FAST) *(u64*)p = __builtin_bit_cast(u64, v);
  else __hip_atomic_store((u64*)p, __builtin_bit_cast(u64, v),
                          __ATOMIC_RELAXED, __HIP_MEMORY_SCOPE_AGENT);
}

// ---- sync: R8-proven, byte-identical primitives ----
// HARD RULE (hangs R5/R9): spin-polls sc0|sc1 (LLC); arrivals agent-scope RMW.
// line words: [0]=h_arr [1]=x_arr [2]=y_arr
__device__ __forceinline__ void poll1(unsigned* p, unsigned tgt) {
  while (__hip_atomic_load(p, __ATOMIC_RELAXED, __HIP_MEMORY_SCOPE_AGENT) < tgt)
    __builtin_amdgcn_s_sleep(1);
}
__device__ __forceinline__ void pollh(unsigned* bar, unsigned ht, unsigned xt, unsigned yt) {
  uint4v v;
  for (;;) {
    asm volatile("global_load_dwordx4 %0, %1, off sc0 sc1\n\ts_waitcnt vmcnt(0)"
                 : "=v"(v) : "v"(bar) : "memory");
    if (v.x >= ht && v.y >= xt && v.z >= yt) return;
    __builtin_amdgcn_s_sleep(1);
  }
}
__device__ __forceinline__ void arrive(unsigned* ctr) {
  asm volatile("s_waitcnt vmcnt(0)" ::: "memory");
  __syncthreads();
  if (threadIdx.x == 0)
    __hip_atomic_fetch_add(ctr, 1u, __ATOMIC_RELAXED, __HIP_MEMORY_SCOPE_AGENT);
}

// ---------------- setup: z ring init (z_0 full; x parts of z_1, z_2), zero sync ----------------
__global__ void elman_setup(const float* __restrict__ h0, const float* __restrict__ xs,
                            unsigned short* __restrict__ zT, unsigned* __restrict__ bars) {
  const int b = blockIdx.x;
  if (b == 0) {
    for (int j = threadIdx.x; j < 1024; j += blockDim.x) bars[j] = 0u;
  }
  for (int k = threadIdx.x; k < KZ; k += blockDim.x) {   // buf0 = z_0
    const float v = (k < HID) ? h0[k] : xs[(size_t)(k - HID) * NB + b];
    zT[(size_t)b * KZ + k] = f2bf(v);
  }
  for (int i = threadIdx.x; i < INP; i += blockDim.x) {  // buf1.x = x_1, buf2.x = x_2
    zT[(size_t)ZSZ     + (size_t)b * KZ + HID + i] = f2bf(xs[(size_t)(INP     + i) * NB + b]);
    zT[(size_t)2 * ZSZ + (size_t)b * KZ + HID + i] = f2bf(xs[(size_t)(2 * INP + i) * NB + b]);
  }
}

// LDS: single-pass reduce buffer, 8 waves x 2 halves x [32 cols][stride 36]
#define PSTR 36
#define PWSZ (32 * PSTR)

// ---------------- phase loop (R8 bodies + staged vmcnt + single-pass reduce) ----------------
// 256 WGs x 512 threads. slice = wg & 7 (32 WGs: 16 h + 8 y + 8 x), 6-deep z ring.
// Phase t:  h: z_{t+1}.h <- sigm(Wh @ z_t)   poll: h>=16t, x>=8(t-2), y>=8(t-4)
//           y: out[t-1] <- sigm(Wy @ z_t.h)  poll: h>=16t                (t>=1)
//           x: z_{t+3}.x <- xs[t+3]          poll: h>=16(t-2)            (t<=T-4)
// Hazards (ring 6): h@t writes buf (t+1)%6 (held z_{t-5}): h-readers by h>=16t,
//   y@t-5 by y>=8(t-4); x wrote same buf's x-part at t-2 (disjoint rows).
// x@t writes buf (t+3)%6 (held z_{t-3}): h@t-3 readers by h>=16(t-2); y reads
//   h-part only (disjoint).  h@t reads z_t.x (written x@t-3) by x>=8(t-2);
//   z_1.x/z_2.x from setup.  All gates target strictly-earlier phases; every
//   role arrives unconditionally each phase => deadlock-free by induction.
template <bool FAST>
__device__ __forceinline__ void run_phases(
    const float* __restrict__ xs,
    const float* __restrict__ Wh, const float* __restrict__ bh,
    const float* __restrict__ Wy, const float* __restrict__ by,
    unsigned short* __restrict__ zT, float* __restrict__ out,
    unsigned* line, float* P, int wg, int tid) {
  const int w = tid >> 6, lane = tid & 63;
  const int lr = lane & 15, lk = lane >> 4;

  if (wg < 128) {
    // ================= h role =================
    const int m0 = (wg >> 3) * 64;
    const int n0 = (wg & 7) * 32;
    const int kw = w * 192;
    bf16x8 A[4][6];                         // resident W_h fragments
#pragma unroll
    for (int mt = 0; mt < 4; ++mt)
#pragma unroll
      for (int kc = 0; kc < 6; ++kc) {
        const float* wp = Wh + (size_t)(m0 + mt * 16 + lr) * KZ + kw + kc * 32 + lk * 8;
        const f32x4 f0 = *(const f32x4*)wp;
        const f32x4 f1 = *(const f32x4*)(wp + 4);
        ushort8 a;
#pragma unroll
        for (int e = 0; e < 4; ++e) { a[e] = f2bf(f0[e]); a[4 + e] = f2bf(f1[e]); }
        A[mt][kc] = __builtin_bit_cast(bf16x8, a);
      }
    const int lcol = tid >> 4;
    const int r2 = (tid & 15) * 2;
    f32x2 bias[2];
#pragma unroll
    for (int hf = 0; hf < 2; ++hf) bias[hf] = *(const f32x2*)&bh[m0 + hf * 32 + r2];
    float* Pw = P + w * (2 * PWSZ);

    for (int t = 0; t <= T_STEPS; ++t) {
      if (t < T_STEPS) {
        const unsigned short* zc = zT + (size_t)(t % ZR) * ZSZ;
        unsigned short* zn = zT + (size_t)((t + 1) % ZR) * ZSZ;
        if (t >= 1) {
          if (tid == 0) pollh(line, 16u * (unsigned)t,
                              (t >= 3) ? 8u * (unsigned)(t - 2) : 0u,
                              (t >= 5) ? 8u * (unsigned)(t - 4) : 0u);
          __syncthreads();
        }
        const unsigned short* zb = zc + (size_t)(n0 + lr) * KZ + kw + lk * 8;
        // issue ALL 12 loads in consumption order; counted waits overlap loads with MFMA
        bf16x8 bfr[6][2];
#pragma unroll
        for (int kc = 0; kc < 6; ++kc)
#pragma unroll
          for (int nt = 0; nt < 2; ++nt) {
            if constexpr (FAST) ZLOAD_FAST(bfr[kc][nt], zb + nt * (16 * KZ) + kc * 32);
            else                ZLOAD_SLOW(bfr[kc][nt], zb + nt * (16 * KZ) + kc * 32);
          }
        f32x4 acc[4][2];
#pragma unroll
        for (int mt = 0; mt < 4; ++mt)
#pragma unroll
          for (int nt = 0; nt < 2; ++nt) acc[mt][nt] = (f32x4){0.f, 0.f, 0.f, 0.f};
        ZWAITN(8);
#pragma unroll
        for (int kc = 0; kc < 2; ++kc)
#pragma unroll
          for (int nt = 0; nt < 2; ++nt)
#pragma unroll
            for (int mt = 0; mt < 4; ++mt)
              acc[mt][nt] = __builtin_amdgcn_mfma_f32_16x16x32_bf16(A[mt][kc], bfr[kc][nt], acc[mt][nt], 0, 0, 0);
        ZWAITN(4);
#pragma unroll
        for (int kc = 2; kc < 4; ++kc)
#pragma unroll
          for (int nt = 0; nt < 2; ++nt)
#pragma unroll
            for (int mt = 0; mt < 4; ++mt)
              acc[mt][nt] = __builtin_amdgcn_mfma_f32_16x16x32_bf16(A[mt][kc], bfr[kc][nt], acc[mt][nt], 0, 0, 0);
        ZWAITN(0);
#pragma unroll
        for (int kc = 4; kc < 6; ++kc)
#pragma unroll
          for (int nt = 0; nt < 2; ++nt)
#pragma unroll
            for (int mt = 0; mt < 4; ++mt)
              acc[mt][nt] = __builtin_amdgcn_mfma_f32_16x16x32_bf16(A[mt][kc], bfr[kc][nt], acc[mt][nt], 0, 0, 0);
        // single-pass cross-wave K reduction (both 32-row halves, one barrier)
#pragma unroll
        for (int hf = 0; hf < 2; ++hf)
#pragma unroll
          for (int mp = 0; mp < 2; ++mp)
#pragma unroll
            for (int nt = 0; nt < 2; ++nt)
              *(f32x4*)&Pw[hf * PWSZ + (nt * 16 + lr) * PSTR + mp * 16 + lk * 4] = acc[hf * 2 + mp][nt];
        __syncthreads();
#pragma unroll
        for (int hf = 0; hf < 2; ++hf) {
          f32x2 s = {0.f, 0.f};
#pragma unroll
          for (int ww = 0; ww < 8; ++ww)
            s += *(const f32x2*)&P[ww * (2 * PWSZ) + hf * PWSZ + lcol * PSTR + r2];
          s += bias[hf];
          ushort2v o2;
          o2[0] = f2bf(sigm(s[0]));
          o2[1] = f2bf(sigm(s[1]));
          zst4<FAST>(zn + (size_t)(n0 + lcol) * KZ + m0 + hf * 32 + r2, o2);
        }
      }
      arrive(line + 0);
    }

  } else if (wg < 192) {
    // ================= y role =================
    const int idx = wg - 128;
    const int m0 = (idx >> 3) * 64;
    const int n0 = (idx & 7) * 32;
    const int kw = w * 128;
    bf16x8 A[4][4];                         // resident W_y fragments
#pragma unroll
    for (int mt = 0; mt < 4; ++mt)
#pragma unroll
      for (int kc = 0; kc < 4; ++kc) {
        const float* wp = Wy + (size_t)(m0 + mt * 16 + lr) * HID + kw + kc * 32 + lk * 8;
        const f32x4 f0 = *(const f32x4*)wp;
        const f32x4 f1 = *(const f32x4*)(wp + 4);
        ushort8 a;
#pragma unroll
        for (int e = 0; e < 4; ++e) { a[e] = f2bf(f0[e]); a[4 + e] = f2bf(f1[e]); }
        A[mt][kc] = __builtin_bit_cast(bf16x8, a);
      }
    const int lcol = tid & 31;
    const int r2 = (tid >> 5) * 2;
    f32x2 bias[2];
#pragma unroll
    for (int hf = 0; hf < 2; ++hf) bias[hf] = *(const f32x2*)&by[m0 + hf * 32 + r2];
    float* Pw = P + w * (2 * PWSZ);

    for (int t = 0; t <= T_STEPS; ++t) {
      if (t >= 1) {
        const unsigned short* zc = zT + (size_t)(t % ZR) * ZSZ;
        if (tid == 0) poll1(line + 0, 16u * (unsigned)t);
        __syncthreads();
        const unsigned short* zb = zc + (size_t)(n0 + lr) * KZ + kw + lk * 8;
        bf16x8 fb[4][2];
#pragma unroll
        for (int kc = 0; kc < 4; ++kc)
#pragma unroll
          for (int nt = 0; nt < 2; ++nt) {
            if constexpr (FAST) ZLOAD_FAST(fb[kc][nt], zb + nt * (16 * KZ) + kc * 32);
            else                ZLOAD_SLOW(fb[kc][nt], zb + nt * (16 * KZ) + kc * 32);
          }
        f32x4 acc[4][2];
#pragma unroll
        for (int mt = 0; mt < 4; ++mt)
#pragma unroll
          for (int nt = 0; nt < 2; ++nt) acc[mt][nt] = (f32x4){0.f, 0.f, 0.f, 0.f};
        ZWAITN(4);
#pragma unroll
        for (int kc = 0; kc < 2; ++kc)
#pragma unroll
          for (int nt = 0; nt < 2; ++nt)
#pragma unroll
            for (int mt = 0; mt < 4; ++mt)
              acc[mt][nt] = __builtin_amdgcn_mfma_f32_16x16x32_bf16(A[mt][kc], fb[kc][nt], acc[mt][nt], 0, 0, 0);
        ZWAITN(0);
#pragma unroll
        for (int kc = 2; kc < 4; ++kc)
#pragma unroll
          for (int nt = 0; nt < 2; ++nt)
#pragma unroll
            for (int mt = 0; mt < 4; ++mt)
              acc[mt][nt] = __builtin_amdgcn_mfma_f32_16x16x32_bf16(A[mt][kc], fb[kc][nt], acc[mt][nt], 0, 0, 0);
        float* op = out + (size_t)(t - 1) * (WID * NB);
        // single-pass reduction
#pragma unroll
        for (int hf = 0; hf < 2; ++hf)
#pragma unroll
          for (int mp = 0; mp < 2; ++mp)
#pragma unroll
            for (int nt = 0; nt < 2; ++nt)
              *(f32x4*)&Pw[hf * PWSZ + (nt * 16 + lr) * PSTR + mp * 16 + lk * 4] = acc[hf * 2 + mp][nt];
        __syncthreads();
#pragma unroll
        for (int hf = 0; hf < 2; ++hf) {
          f32x2 s = {0.f, 0.f};
#pragma unroll
          for (int ww = 0; ww < 8; ++ww)
            s += *(const f32x2*)&P[ww * (2 * PWSZ) + hf * PWSZ + lcol * PSTR + r2];
          s += bias[hf];
          const int row = m0 + hf * 32 + r2;
          op[(size_t)(row + 0) * NB + n0 + lcol] = sigm(s[0]);  // cached; flushed at kernel end
          op[(size_t)(row + 1) * NB + n0 + lcol] = sigm(s[1]);
        }
      }
      arrive(line + 2);
    }

  } else {
    // ================= x role (three phases ahead: writes x_{t+3}) =================
    const int xi = wg - 192;
    const int i0 = (xi >> 3) * 64;
    const int b0 = (xi & 7) * 32;
    const int c = tid & 31, rb = tid >> 5;
    for (int t = 0; t <= T_STEPS; ++t) {
      if (t <= T_STEPS - 4) {
        unsigned short* zx = zT + (size_t)((t + 3) % ZR) * ZSZ;
        const float* xp = xs + (size_t)(t + 3) * (INP * NB) + (size_t)(i0 + rb * 4) * NB + b0 + c;
        ushort4v o;
#pragma unroll
        for (int j = 0; j < 4; ++j) o[j] = f2bf(xp[(size_t)j * NB]);
        // anti-dep on buf (t+3)%6 (held z_{t-3}): h@t-3 readers done (2-phase slack)
        if (t >= 3 && tid == 0) poll1(line + 0, 16u * (unsigned)(t - 2));
        __syncthreads();
        zst8<FAST>(zx + (size_t)(b0 + c) * KZ + HID + i0 + rb * 4, o);
      }
      arrive(line + 1);
    }
  }
}

// ---------------- persistent sequential kernel ----------------
__global__ void __launch_bounds__(512, 2) elman_seq(
    const float* __restrict__ xs,
    const float* __restrict__ Wh, const float* __restrict__ bh,
    const float* __restrict__ Wy, const float* __restrict__ by,
    unsigned short* __restrict__ zT, float* __restrict__ out,
    unsigned* __restrict__ bars) {
  __shared__ float P[16 * PWSZ];   // 72 KiB single-pass reduction buffer
  __shared__ unsigned modeSh;
  const int wg = blockIdx.x, tid = threadIdx.x;
  unsigned* line = bars + (wg & 7) * 64;
  unsigned* xcds = bars + 512;
  unsigned* hbar = bars + 768;

  // one-shot handshake (R8-proven): slice on ONE XCD? -> z data via L2
  unsigned xcc;
  asm volatile("s_getreg_b32 %0, hwreg(HW_REG_XCC_ID)" : "=s"(xcc));
  if (tid == 0) {
    __hip_atomic_store(&xcds[wg], xcc + 1u, __ATOMIC_RELAXED, __HIP_MEMORY_SCOPE_AGENT);
    asm volatile("s_waitcnt vmcnt(0)" ::: "memory");
    __hip_atomic_fetch_add(hbar, 1u, __ATOMIC_RELAXED, __HIP_MEMORY_SCOPE_AGENT);
    while (__hip_atomic_load(hbar, __ATOMIC_RELAXED, __HIP_MEMORY_SCOPE_AGENT) < 256u)
      __builtin_amdgcn_s_sleep(1);
    const unsigned v0 = __hip_atomic_load(&xcds[wg & 7], __ATOMIC_RELAXED, __HIP_MEMORY_SCOPE_AGENT);
    unsigned m = 1u;
    for (int j = 1; j < 32; ++j)
      m &= (__hip_atomic_load(&xcds[(wg & 7) + 8 * j], __ATOMIC_RELAXED,
                              __HIP_MEMORY_SCOPE_AGENT) == v0) ? 1u : 0u;
    modeSh = m;
  }
  __syncthreads();

  if (modeSh)
    run_phases<true >(xs, Wh, bh, Wy, by, zT, out, line, P, wg, tid);
  else
    run_phases<false>(xs, Wh, bh, Wy, by, zT, out, line, P, wg, tid);
}

// ---------------- host launch ----------------
extern "C" void kernel_launch(void* const* d_in, const int* in_sizes, int n_in,
                              void* d_out, int out_size, void* d_ws, size_t ws_size,
                              hipStream_t stream) {
  (void)in_sizes; (void)n_in; (void)out_size; (void)ws_size;
  const float* xs  = (const float*)d_in[0];
  const float* W_h = (const float*)d_in[1];
  const float* b_h = (const float*)d_in[2];
  const float* W_y = (const float*)d_in[3];
  const float* b_y = (const float*)d_in[4];
  const float* h0  = (const float*)d_in[5];
  float* out = (float*)d_out;

  // ws layout: zT bf16 [6][256][1536] ring | bars/xcds/hbar (1024 u32)
  unsigned short* zT = (unsigned short*)d_ws;
  unsigned* bars = (unsigned*)(zT + (size_t)ZR * ZSZ);

  elman_setup<<<dim3(NB), dim3(256), 0, stream>>>(h0, xs, zT, bars);

  void* args[8];
  args[0] = (void*)&xs;  args[1] = (void*)&W_h; args[2] = (void*)&b_h;
  args[3] = (void*)&W_y; args[4] = (void*)&b_y; args[5] = (void*)&zT;
  args[6] = (void*)&out; args[7] = (void*)&bars;
  hipLaunchCooperativeKernel((void*)elman_seq, dim3(256), dim3(512), args, 0u, stream);
}